// Round 8
// baseline (671.417 us; speedup 1.0000x reference)
//
#include <hip/hip_runtime.h>
#include <math.h>

#define CDIM 256
#define RBFD 16
#define NATOMS 10000

__device__ __forceinline__ float dot44(float4 a, float4 b) {
  return a.x * b.x + a.y * b.y + a.z * b.z + a.w * b.w;
}

// ---------------------------------------------------------------------------
// Edge-streaming gather, R8 (R7 + compile fix): NO CSR, NO random reads.
// One wave per edge (grid-stride). x is read in (nearly) sequential edge
// order -> streaming HBM BW. Results scatter into acc[atom][c] via
// fire-and-forget f32 atomics: lane l owns channels {l, 64+l, 128+l, 192+l},
// so each of the 4 atomic instructions per edge is a dense 64-lane x 4B =
// 256 B contiguous burst. acc (10 MB) is L2-resident; expected concurrent
// edges per atom ~0.4. 2-deep ping-pong (static register stages) covers
// load latency.
//   acc[a][c] += (b_rbf[c] + rbf[e]·w_rbf[c]) * x[e][c]
// ---------------------------------------------------------------------------
__global__ __launch_bounds__(256, 3) void edge_gather_kernel(
    const float* __restrict__ x, const float* __restrict__ rbf,
    const int* __restrict__ eidx, const float* __restrict__ w_rbf,
    const float* __restrict__ b_rbf, float* __restrict__ acc, int E) {
  const int tid = threadIdx.x;
  const int lane = tid & 63;
  const int wid = __builtin_amdgcn_readfirstlane(
      (int)((blockIdx.x * blockDim.x + tid) >> 6));
  const int nw = (int)((gridDim.x * blockDim.x) >> 6);

  // Lane's 4 channels: l, 64+l, 128+l, 192+l. Hoist their w_rbf rows + bias.
  float4 w0q0, w0q1, w0q2, w0q3;  // row l
  float4 w1q0, w1q1, w1q2, w1q3;  // row 64+l
  float4 w2q0, w2q1, w2q2, w2q3;  // row 128+l
  float4 w3q0, w3q1, w3q2, w3q3;  // row 192+l
  {
    const float4* r;
    r = (const float4*)(w_rbf + (size_t)(lane)*RBFD);
    w0q0 = r[0]; w0q1 = r[1]; w0q2 = r[2]; w0q3 = r[3];
    r = (const float4*)(w_rbf + (size_t)(64 + lane) * RBFD);
    w1q0 = r[0]; w1q1 = r[1]; w1q2 = r[2]; w1q3 = r[3];
    r = (const float4*)(w_rbf + (size_t)(128 + lane) * RBFD);
    w2q0 = r[0]; w2q1 = r[1]; w2q2 = r[2]; w2q3 = r[3];
    r = (const float4*)(w_rbf + (size_t)(192 + lane) * RBFD);
    w3q0 = r[0]; w3q1 = r[1]; w3q2 = r[2]; w3q3 = r[3];
  }
  const float b0 = b_rbf[lane];
  const float b1 = b_rbf[64 + lane];
  const float b2 = b_rbf[128 + lane];
  const float b3 = b_rbf[192 + lane];

  // Ping-pong stages (all statically named; no runtime-indexed arrays).
  int aA, aB;
  float xA0, xA1, xA2, xA3, xB0, xB1, xB2, xB3;
  float4 rA0, rA1, rA2, rA3, rB0, rB1, rB2, rB3;

#define LOADE(S, e)                                                          \
  {                                                                          \
    a##S = __builtin_amdgcn_readfirstlane(eidx[e]);                          \
    const float* xp_ = x + (size_t)(e)*CDIM + lane;                          \
    x##S##0 = xp_[0];                                                        \
    x##S##1 = xp_[64];                                                       \
    x##S##2 = xp_[128];                                                      \
    x##S##3 = xp_[192];                                                      \
    const float4* q_ = (const float4*)(rbf + (size_t)(e)*RBFD);              \
    r##S##0 = q_[0];                                                         \
    r##S##1 = q_[1];                                                         \
    r##S##2 = q_[2];                                                         \
    r##S##3 = q_[3];                                                         \
  }

#define FIRE(S)                                                              \
  {                                                                          \
    const float f0_ = b0 + dot44(w0q0, r##S##0) + dot44(w0q1, r##S##1) +     \
                      dot44(w0q2, r##S##2) + dot44(w0q3, r##S##3);           \
    const float f1_ = b1 + dot44(w1q0, r##S##0) + dot44(w1q1, r##S##1) +     \
                      dot44(w1q2, r##S##2) + dot44(w1q3, r##S##3);           \
    const float f2_ = b2 + dot44(w2q0, r##S##0) + dot44(w2q1, r##S##1) +     \
                      dot44(w2q2, r##S##2) + dot44(w2q3, r##S##3);           \
    const float f3_ = b3 + dot44(w3q0, r##S##0) + dot44(w3q1, r##S##1) +     \
                      dot44(w3q2, r##S##2) + dot44(w3q3, r##S##3);           \
    float* d_ = acc + (size_t)a##S * CDIM + lane;                            \
    atomicAdd(d_ + 0, f0_ * x##S##0);                                        \
    atomicAdd(d_ + 64, f1_ * x##S##1);                                       \
    atomicAdd(d_ + 128, f2_ * x##S##2);                                      \
    atomicAdd(d_ + 192, f3_ * x##S##3);                                      \
  }

  int e = wid;
  if (e >= E) return;
  LOADE(A, e)
  while (true) {
    const int en = e + nw;
    if (en < E) {
      LOADE(B, en)
      FIRE(A)
      const int en2 = en + nw;
      if (en2 < E) {
        LOADE(A, en2)
        FIRE(B)
        e = en2;
        continue;
      } else {
        FIRE(B)
        break;
      }
    } else {
      FIRE(A)
      break;
    }
  }

#undef LOADE
#undef FIRE
}

// ---------------------------------------------------------------------------
// Transpose w1, w2 (256x256) into k-major layout.
// ---------------------------------------------------------------------------
__global__ void transpose_kernel(const float* __restrict__ w1,
                                 const float* __restrict__ w2,
                                 float* __restrict__ w1T,
                                 float* __restrict__ w2T) {
  __shared__ float tile[32][33];
  const float* src = blockIdx.z ? w2 : w1;
  float* dst = blockIdx.z ? w2T : w1T;
  const int bx = blockIdx.x * 32;
  const int by = blockIdx.y * 32;
  const int tx = threadIdx.x, ty = threadIdx.y;  // (32, 8)
#pragma unroll
  for (int i = 0; i < 32; i += 8)
    tile[ty + i][tx] = src[(size_t)(by + ty + i) * CDIM + bx + tx];
  __syncthreads();
#pragma unroll
  for (int i = 0; i < 32; i += 8)
    dst[(size_t)(bx + ty + i) * CDIM + by + tx] = tile[tx][ty + i];
}

// ---------------------------------------------------------------------------
// Fused per-atom MLP. Block = 256 threads, 32 atoms. Thread tile = 4 atoms x
// 8 channels, channels {4tc..4tc+3} and {128+4tc..128+4tc+3} so WK
// ds_read_b128s are lane-consecutive (conflict-free).
// ---------------------------------------------------------------------------
__global__ __launch_bounds__(256, 2) void mlp_kernel(
    const float* __restrict__ hin, const float* __restrict__ w1T,
    const float* __restrict__ b1, const float* __restrict__ w2T,
    const float* __restrict__ b2, const float* __restrict__ w3,
    const float* __restrict__ b3, float* __restrict__ out, int natoms) {
  __shared__ float H[32 * 256];   // [atom][k]
  __shared__ float WK[32 * 256];  // [k_local][c_out]; reused as reduce buffer
  const int tid = threadIdx.x;
  const int tc = tid & 31;
  const int ta = tid >> 5;
  const int a0 = blockIdx.x * 32;
  const int cA = tc * 4;        // channels cA..cA+3
  const int cB = 128 + tc * 4;  // channels cB..cB+3

  // Stage H (zero-pad invalid atoms in last block).
  {
    const float4* src = (const float4*)hin + (size_t)a0 * 64;
    float4* Hv = (float4*)H;
#pragma unroll
    for (int i = 0; i < 8; ++i) {
      const int idx = tid + i * 256;  // 0..2047
      const int ga = a0 + (idx >> 6);
      Hv[idx] = (ga < natoms) ? src[idx] : make_float4(0.f, 0.f, 0.f, 0.f);
    }
  }

  float s[4][8];  // post-silu activations of current layer

#pragma unroll 1
  for (int layer = 0; layer < 2; ++layer) {
    const float* wT = (layer == 0) ? w1T : w2T;
    const float* bias = (layer == 0) ? b1 : b2;
    float r[4][8];
    const float4 bA = *(const float4*)(bias + cA);
    const float4 bB = *(const float4*)(bias + cB);
#pragma unroll
    for (int a = 0; a < 4; ++a) {
      r[a][0] = bA.x; r[a][1] = bA.y; r[a][2] = bA.z; r[a][3] = bA.w;
      r[a][4] = bB.x; r[a][5] = bB.y; r[a][6] = bB.z; r[a][7] = bB.w;
    }

    for (int k0 = 0; k0 < 256; k0 += 32) {
      __syncthreads();  // previous chunk fully consumed
      {
        const float4* wsrc = (const float4*)(wT + (size_t)k0 * CDIM);
        float4* WKv = (float4*)WK;
#pragma unroll
        for (int i = 0; i < 8; ++i) WKv[tid + i * 256] = wsrc[tid + i * 256];
      }
      __syncthreads();

#pragma unroll
      for (int kk = 0; kk < 32; kk += 4) {
        float4 ha[4];
#pragma unroll
        for (int a = 0; a < 4; ++a)
          ha[a] = *(const float4*)&H[(ta * 4 + a) * 256 + k0 + kk];
#pragma unroll
        for (int u = 0; u < 4; ++u) {
          const float4 w0 = *(const float4*)&WK[(kk + u) * 256 + cA];
          const float4 w1v = *(const float4*)&WK[(kk + u) * 256 + cB];
#pragma unroll
          for (int a = 0; a < 4; ++a) {
            const float hv = (u == 0) ? ha[a].x
                           : (u == 1) ? ha[a].y
                           : (u == 2) ? ha[a].z : ha[a].w;
            r[a][0] += hv * w0.x;  r[a][1] += hv * w0.y;
            r[a][2] += hv * w0.z;  r[a][3] += hv * w0.w;
            r[a][4] += hv * w1v.x; r[a][5] += hv * w1v.y;
            r[a][6] += hv * w1v.z; r[a][7] += hv * w1v.w;
          }
        }
      }
    }

    // SiLU
#pragma unroll
    for (int a = 0; a < 4; ++a)
#pragma unroll
      for (int j = 0; j < 8; ++j) {
        const float v = r[a][j];
        s[a][j] = v / (1.0f + __expf(-v));
      }

    if (layer == 0) {
      __syncthreads();  // all H reads of layer 1 done
#pragma unroll
      for (int a = 0; a < 4; ++a) {
        *(float4*)&H[(ta * 4 + a) * 256 + cA] =
            make_float4(s[a][0], s[a][1], s[a][2], s[a][3]);
        *(float4*)&H[(ta * 4 + a) * 256 + cB] =
            make_float4(s[a][4], s[a][5], s[a][6], s[a][7]);
      }
    }
  }

  // Layer 3: per-atom dot with w3, reduce across the 32 channel groups.
  const float4 w3a = *(const float4*)(w3 + cA);
  const float4 w3b = *(const float4*)(w3 + cB);
  float part[4];
#pragma unroll
  for (int a = 0; a < 4; ++a) {
    part[a] = s[a][0] * w3a.x + s[a][1] * w3a.y + s[a][2] * w3a.z +
              s[a][3] * w3a.w + s[a][4] * w3b.x + s[a][5] * w3b.y +
              s[a][6] * w3b.z + s[a][7] * w3b.w;
  }
  __syncthreads();  // WK reads done; reuse as reduce buffer [32][33]
  float* red = WK;
#pragma unroll
  for (int a = 0; a < 4; ++a) red[(ta * 4 + a) * 33 + tc] = part[a];
  __syncthreads();
  if (tid < 32) {
    float sum = 0.f;
#pragma unroll
    for (int j = 0; j < 32; ++j) sum += red[tid * 33 + j];
    const int ga = a0 + tid;
    if (ga < natoms) out[ga] = sum + b3[0];
  }
}

extern "C" void kernel_launch(void* const* d_in, const int* in_sizes, int n_in,
                              void* d_out, int out_size, void* d_ws,
                              size_t ws_size, hipStream_t stream) {
  const float* x = (const float*)d_in[0];
  const float* rbf = (const float*)d_in[1];
  const int* eidx = (const int*)d_in[3];
  const float* w_rbf = (const float*)d_in[4];
  const float* b_rbf = (const float*)d_in[5];
  const float* w1 = (const float*)d_in[6];
  const float* b1 = (const float*)d_in[7];
  const float* w2 = (const float*)d_in[8];
  const float* b2 = (const float*)d_in[9];
  const float* w3 = (const float*)d_in[10];
  const float* b3 = (const float*)d_in[11];
  float* out = (float*)d_out;
  const int E = in_sizes[0] / CDIM;

  // Workspace layout (CSR arrays no longer needed).
  char* p = (char*)d_ws;
  float* acc = (float*)p;              p += (size_t)NATOMS * CDIM * sizeof(float);
  float* w1T = (float*)p;              p += CDIM * CDIM * sizeof(float);
  float* w2T = (float*)p;              p += CDIM * CDIM * sizeof(float);

  (void)hipMemsetAsync(acc, 0, (size_t)NATOMS * CDIM * sizeof(float), stream);
  transpose_kernel<<<dim3(8, 8, 2), dim3(32, 8), 0, stream>>>(w1, w2, w1T, w2T);
  edge_gather_kernel<<<1024, 256, 0, stream>>>(x, rbf, eidx, w_rbf, b_rbf, acc,
                                               E);
  mlp_kernel<<<(NATOMS + 31) / 32, 256, 0, stream>>>(acc, w1T, b1, w2T, b2, w3,
                                                     b3, out, NATOMS);
}

// Round 9
// 627.847 us; speedup vs baseline: 1.0694x; 1.0694x over previous
//
#include <hip/hip_runtime.h>
#include <math.h>

#define CDIM 256
#define RBFD 16
#define NATOMS 10000

__device__ __forceinline__ float dot44(float4 a, float4 b) {
  return a.x * b.x + a.y * b.y + a.z * b.z + a.w * b.w;
}

// ---------------------------------------------------------------------------
// CSR build: histogram -> single-block exclusive scan -> scatter edge ids.
// ---------------------------------------------------------------------------
__global__ void hist_kernel(const int* __restrict__ eidx, int* __restrict__ counts,
                            int E) {
  const int i = blockIdx.x * blockDim.x + threadIdx.x;
  if (i < E) atomicAdd(&counts[eidx[i]], 1);
}

__global__ void scan_kernel(const int* __restrict__ counts,
                            int* __restrict__ offsets, int* __restrict__ cursor) {
  __shared__ int part[256];
  const int t = threadIdx.x;
  const int CH = (NATOMS + 255) / 256;  // 40
  const int base = t * CH;
  const int n = min(CH, max(0, NATOMS - base));
  int s = 0;
  for (int j = 0; j < n; ++j) s += counts[base + j];
  part[t] = s;
  __syncthreads();
  for (int off = 1; off < 256; off <<= 1) {
    int v = 0;
    if (t >= off) v = part[t - off];
    __syncthreads();
    part[t] += v;
    __syncthreads();
  }
  int run = part[t] - s;  // exclusive start for this chunk
  for (int j = 0; j < n; ++j) {
    offsets[base + j] = run;
    cursor[base + j] = run;
    run += counts[base + j];
  }
  if (t == 255) offsets[NATOMS] = part[255];
}

__global__ void scatter_kernel(const int* __restrict__ eidx,
                               int* __restrict__ cursor, int* __restrict__ elist,
                               int E) {
  const int i = blockIdx.x * blockDim.x + threadIdx.x;
  if (i < E) {
    const int a = eidx[i];
    const int pos = atomicAdd(&cursor[a], 1);
    elist[pos] = i;
  }
}

// ---------------------------------------------------------------------------
// Gather phase (best-measured, R5): one BLOCK per atom, 4 waves; wave w owns
// channels [64w, 64w+64), lane = one channel. Per-lane state is tiny (filter
// row = 16 VGPR, stage = 17 VGPR); 3-stage rotating pipeline, no LDS, no
// syncthreads, no inline asm. Each wave stores its disjoint 256 B slice of
// acc directly (4 B/lane, coalesced).
//   acc[a][c] = sum_{e in bucket(a)} (b_rbf[c] + rbf[e]·w_rbf[c]) * x[e][c]
// Measured: gather ~150 us; random-row fetch rate ~1.2-2.4 TB/s HBM-side,
// invariant across 5 structural designs (R1-R8) -> empirical pattern ceiling.
// ---------------------------------------------------------------------------
__global__ __launch_bounds__(256, 5) void gather_kernel(
    const float* __restrict__ x, const float* __restrict__ rbf,
    const int* __restrict__ elist, const int* __restrict__ offsets,
    const float* __restrict__ w_rbf, const float* __restrict__ b_rbf,
    float* __restrict__ acc) {
  const int tid = threadIdx.x;
  const int lane = tid & 63;
  const int w = tid >> 6;  // wave id within block: channel group
  const int atom = blockIdx.x;
  const int ch = w * 64 + lane;  // this lane's channel

  const int start = __builtin_amdgcn_readfirstlane(offsets[atom]);
  const int end = __builtin_amdgcn_readfirstlane(offsets[atom + 1]);

  // This lane's filter row of w_rbf (16 floats) + bias.
  float4 wv0, wv1, wv2, wv3;
  {
    const float4* wr = (const float4*)(w_rbf + (size_t)ch * RBFD);
    wv0 = wr[0];
    wv1 = wr[1];
    wv2 = wr[2];
    wv3 = wr[3];
  }
  const float bb = b_rbf[ch];

  if (end <= start) {  // empty bucket
    acc[(size_t)atom * CDIM + ch] = 0.f;
    return;
  }
  const int last = end - 1;

  float sumA = 0.f, sumB = 0.f, sumC = 0.f;

  // Rotating stage registers (x scalar + full rbf row per stage).
  float xA, xB, xC;
  float4 rA0, rA1, rA2, rA3;
  float4 rB0, rB1, rB2, rB3;
  float4 rC0, rC1, rC2, rC3;

#define LOADD(S, eid)                                                        \
  {                                                                          \
    x##S = x[(size_t)(eid)*CDIM + ch]; /* HBM-heavy stream first */          \
    const float4* q_ = (const float4*)(rbf + (size_t)(eid)*RBFD);            \
    r##S##0 = q_[0];                                                         \
    r##S##1 = q_[1];                                                         \
    r##S##2 = q_[2];                                                         \
    r##S##3 = q_[3];                                                         \
  }

#define COMPUTE(S, sum)                                                      \
  {                                                                          \
    const float f_ = bb + dot44(wv0, r##S##0) + dot44(wv1, r##S##1) +        \
                     dot44(wv2, r##S##2) + dot44(wv3, r##S##3);              \
    sum += f_ * x##S;                                                        \
  }

  // Prologue: ids for edges 0,1,2 resolved; data for edges 0,1 in flight.
  int idA = __builtin_amdgcn_readfirstlane(elist[start]);
  int idB = __builtin_amdgcn_readfirstlane(elist[min(start + 1, last)]);
  int idC = __builtin_amdgcn_readfirstlane(elist[min(start + 2, last)]);
  LOADD(A, idA)
  LOADD(B, idB)

  int i = start;
  for (; i + 3 <= end; i += 3) {
    idA = __builtin_amdgcn_readfirstlane(elist[min(i + 3, last)]);
    LOADD(C, idC)   // data for edge i+2 (id resolved last trip)
    COMPUTE(A, sumA)  // edge i
    idB = __builtin_amdgcn_readfirstlane(elist[min(i + 4, last)]);
    LOADD(A, idA)   // data for edge i+3
    COMPUTE(B, sumB)  // edge i+1
    idC = __builtin_amdgcn_readfirstlane(elist[min(i + 5, last)]);
    LOADD(B, idB)   // data for edge i+4
    COMPUTE(C, sumC)  // edge i+2
  }
  // Tail: 0..2 edges remain, already loaded in stages A,B.
  const int k = end - i;
  if (k >= 1) COMPUTE(A, sumA)
  if (k >= 2) COMPUTE(B, sumB)

#undef LOADD
#undef COMPUTE

  acc[(size_t)atom * CDIM + ch] = sumA + sumB + sumC;
}

// ---------------------------------------------------------------------------
// Transpose w1, w2 (256x256) into k-major layout.
// ---------------------------------------------------------------------------
__global__ void transpose_kernel(const float* __restrict__ w1,
                                 const float* __restrict__ w2,
                                 float* __restrict__ w1T,
                                 float* __restrict__ w2T) {
  __shared__ float tile[32][33];
  const float* src = blockIdx.z ? w2 : w1;
  float* dst = blockIdx.z ? w2T : w1T;
  const int bx = blockIdx.x * 32;
  const int by = blockIdx.y * 32;
  const int tx = threadIdx.x, ty = threadIdx.y;  // (32, 8)
#pragma unroll
  for (int i = 0; i < 32; i += 8)
    tile[ty + i][tx] = src[(size_t)(by + ty + i) * CDIM + bx + tx];
  __syncthreads();
#pragma unroll
  for (int i = 0; i < 32; i += 8)
    dst[(size_t)(bx + ty + i) * CDIM + by + tx] = tile[tx][ty + i];
}

// ---------------------------------------------------------------------------
// Fused per-atom MLP. Block = 256 threads, 32 atoms. Thread tile = 4 atoms x
// 8 channels, channels {4tc..4tc+3} and {128+4tc..128+4tc+3} so WK
// ds_read_b128s are lane-consecutive (conflict-free).
// ---------------------------------------------------------------------------
__global__ __launch_bounds__(256, 2) void mlp_kernel(
    const float* __restrict__ hin, const float* __restrict__ w1T,
    const float* __restrict__ b1, const float* __restrict__ w2T,
    const float* __restrict__ b2, const float* __restrict__ w3,
    const float* __restrict__ b3, float* __restrict__ out, int natoms) {
  __shared__ float H[32 * 256];   // [atom][k]
  __shared__ float WK[32 * 256];  // [k_local][c_out]; reused as reduce buffer
  const int tid = threadIdx.x;
  const int tc = tid & 31;
  const int ta = tid >> 5;
  const int a0 = blockIdx.x * 32;
  const int cA = tc * 4;        // channels cA..cA+3
  const int cB = 128 + tc * 4;  // channels cB..cB+3

  // Stage H (zero-pad invalid atoms in last block).
  {
    const float4* src = (const float4*)hin + (size_t)a0 * 64;
    float4* Hv = (float4*)H;
#pragma unroll
    for (int i = 0; i < 8; ++i) {
      const int idx = tid + i * 256;  // 0..2047
      const int ga = a0 + (idx >> 6);
      Hv[idx] = (ga < natoms) ? src[idx] : make_float4(0.f, 0.f, 0.f, 0.f);
    }
  }

  float s[4][8];  // post-silu activations of current layer

#pragma unroll 1
  for (int layer = 0; layer < 2; ++layer) {
    const float* wT = (layer == 0) ? w1T : w2T;
    const float* bias = (layer == 0) ? b1 : b2;
    float r[4][8];
    const float4 bA = *(const float4*)(bias + cA);
    const float4 bB = *(const float4*)(bias + cB);
#pragma unroll
    for (int a = 0; a < 4; ++a) {
      r[a][0] = bA.x; r[a][1] = bA.y; r[a][2] = bA.z; r[a][3] = bA.w;
      r[a][4] = bB.x; r[a][5] = bB.y; r[a][6] = bB.z; r[a][7] = bB.w;
    }

    for (int k0 = 0; k0 < 256; k0 += 32) {
      __syncthreads();  // previous chunk fully consumed
      {
        const float4* wsrc = (const float4*)(wT + (size_t)k0 * CDIM);
        float4* WKv = (float4*)WK;
#pragma unroll
        for (int i = 0; i < 8; ++i) WKv[tid + i * 256] = wsrc[tid + i * 256];
      }
      __syncthreads();

#pragma unroll
      for (int kk = 0; kk < 32; kk += 4) {
        float4 ha[4];
#pragma unroll
        for (int a = 0; a < 4; ++a)
          ha[a] = *(const float4*)&H[(ta * 4 + a) * 256 + k0 + kk];
#pragma unroll
        for (int u = 0; u < 4; ++u) {
          const float4 w0 = *(const float4*)&WK[(kk + u) * 256 + cA];
          const float4 w1v = *(const float4*)&WK[(kk + u) * 256 + cB];
#pragma unroll
          for (int a = 0; a < 4; ++a) {
            const float hv = (u == 0) ? ha[a].x
                           : (u == 1) ? ha[a].y
                           : (u == 2) ? ha[a].z : ha[a].w;
            r[a][0] += hv * w0.x;  r[a][1] += hv * w0.y;
            r[a][2] += hv * w0.z;  r[a][3] += hv * w0.w;
            r[a][4] += hv * w1v.x; r[a][5] += hv * w1v.y;
            r[a][6] += hv * w1v.z; r[a][7] += hv * w1v.w;
          }
        }
      }
    }

    // SiLU
#pragma unroll
    for (int a = 0; a < 4; ++a)
#pragma unroll
      for (int j = 0; j < 8; ++j) {
        const float v = r[a][j];
        s[a][j] = v / (1.0f + __expf(-v));
      }

    if (layer == 0) {
      __syncthreads();  // all H reads of layer 1 done
#pragma unroll
      for (int a = 0; a < 4; ++a) {
        *(float4*)&H[(ta * 4 + a) * 256 + cA] =
            make_float4(s[a][0], s[a][1], s[a][2], s[a][3]);
        *(float4*)&H[(ta * 4 + a) * 256 + cB] =
            make_float4(s[a][4], s[a][5], s[a][6], s[a][7]);
      }
    }
  }

  // Layer 3: per-atom dot with w3, reduce across the 32 channel groups.
  const float4 w3a = *(const float4*)(w3 + cA);
  const float4 w3b = *(const float4*)(w3 + cB);
  float part[4];
#pragma unroll
  for (int a = 0; a < 4; ++a) {
    part[a] = s[a][0] * w3a.x + s[a][1] * w3a.y + s[a][2] * w3a.z +
              s[a][3] * w3a.w + s[a][4] * w3b.x + s[a][5] * w3b.y +
              s[a][6] * w3b.z + s[a][7] * w3b.w;
  }
  __syncthreads();  // WK reads done; reuse as reduce buffer [32][33]
  float* red = WK;
#pragma unroll
  for (int a = 0; a < 4; ++a) red[(ta * 4 + a) * 33 + tc] = part[a];
  __syncthreads();
  if (tid < 32) {
    float sum = 0.f;
#pragma unroll
    for (int j = 0; j < 32; ++j) sum += red[tid * 33 + j];
    const int ga = a0 + tid;
    if (ga < natoms) out[ga] = sum + b3[0];
  }
}

extern "C" void kernel_launch(void* const* d_in, const int* in_sizes, int n_in,
                              void* d_out, int out_size, void* d_ws,
                              size_t ws_size, hipStream_t stream) {
  const float* x = (const float*)d_in[0];
  const float* rbf = (const float*)d_in[1];
  const int* eidx = (const int*)d_in[3];
  const float* w_rbf = (const float*)d_in[4];
  const float* b_rbf = (const float*)d_in[5];
  const float* w1 = (const float*)d_in[6];
  const float* b1 = (const float*)d_in[7];
  const float* w2 = (const float*)d_in[8];
  const float* b2 = (const float*)d_in[9];
  const float* w3 = (const float*)d_in[10];
  const float* b3 = (const float*)d_in[11];
  float* out = (float*)d_out;
  const int E = in_sizes[0] / CDIM;

  // Workspace layout.
  char* p = (char*)d_ws;
  float* acc = (float*)p;              p += (size_t)NATOMS * CDIM * sizeof(float);
  float* w1T = (float*)p;              p += CDIM * CDIM * sizeof(float);
  float* w2T = (float*)p;              p += CDIM * CDIM * sizeof(float);
  int* counts = (int*)p;               p += NATOMS * sizeof(int);
  int* offsets = (int*)p;              p += (NATOMS + 1) * sizeof(int);
  int* cursor = (int*)p;               p += NATOMS * sizeof(int);
  int* elist = (int*)p;                p += (size_t)E * sizeof(int);

  (void)hipMemsetAsync(counts, 0, NATOMS * sizeof(int), stream);
  hist_kernel<<<(E + 255) / 256, 256, 0, stream>>>(eidx, counts, E);
  scan_kernel<<<1, 256, 0, stream>>>(counts, offsets, cursor);
  scatter_kernel<<<(E + 255) / 256, 256, 0, stream>>>(eidx, cursor, elist, E);
  transpose_kernel<<<dim3(8, 8, 2), dim3(32, 8), 0, stream>>>(w1, w2, w1T, w2T);
  gather_kernel<<<NATOMS, 256, 0, stream>>>(x, rbf, elist, offsets, w_rbf,
                                            b_rbf, acc);
  mlp_kernel<<<(NATOMS + 31) / 32, 256, 0, stream>>>(acc, w1T, b1, w2T, b2, w3,
                                                     b3, out, NATOMS);
}